// Round 17
// baseline (95.750 us; speedup 1.0000x reference)
//
#include <hip/hip_runtime.h>

#define N_NODES 100000
#define FDIM 64
#define BROWS 64                                // rows per bucket
#define NBUCK ((N_NODES + BROWS - 1) / BROWS)   // 1563
#define EDGES_PER_BLK 8192
#define BCAP 1536                               // LDS sort capacity (mean 1024, sd 32)
#define GEMM_BLOCKS ((N_NODES + 63) / 64)       // 1563 (64 rows per 1024-thread block)
#define SCAN_C ((NBUCK + 255) / 256)            // 7 elems/thread for btot scan

// ---------------- ws layout ----------------
// cnts   : off 0       NBUCK*nblk ushort (613 KB; within-bucket exclusive prefixes)
// bbase  : off 656 KB  NBUCK+1 ints (bucket bases + sentinel)
// btot   : off 672 KB  NBUCK ints (bucket totals, via atomics in gemm_count)
// cvbin  : off 1 MB    n_edges int2 {col | rowlo<<20, float_bits(val)}
// yh     : off 14 MB   N_NODES*FDIM bf16 of y = x@W
#define WS_BBASE_OFF (656u * 1024u)
#define WS_BTOT_OFF  (672u * 1024u)
#define WS_CV_OFF    (1024u * 1024u)
#define WS_XH_OFF    (14u * 1024u * 1024u)

__device__ __forceinline__ unsigned short f2bf(float f) {
    unsigned int u = __float_as_uint(f);
    return (unsigned short)((u + 0x7FFFu + ((u >> 16) & 1u)) >> 16);
}
__device__ __forceinline__ float bf2f(unsigned short h) {
    return __uint_as_float((unsigned int)h << 16);
}

// ============ fallback (round-4 verified): fp32 HW atomics ============
__global__ __launch_bounds__(256) void spmm_atomic(
    const float* __restrict__ x, const int* __restrict__ erow,
    const int* __restrict__ ecol, const float* __restrict__ eval,
    float* __restrict__ out, int n_edges)
{
    int tid = blockIdx.x * 256 + threadIdx.x;
    int e = tid >> 4, l = tid & 15;
    if (e >= n_edges) return;
    int row = erow[e], col = ecol[e];
    float v = eval[e];
    const float4 xv = *reinterpret_cast<const float4*>(x + (size_t)col * FDIM + l * 4);
    float* dst = out + (size_t)row * FDIM + l * 4;
    unsafeAtomicAdd(dst + 0, v * xv.x);
    unsafeAtomicAdd(dst + 1, v * xv.y);
    unsafeAtomicAdd(dst + 2, v * xv.z);
    unsafeAtomicAdd(dst + 3, v * xv.w);
}

// ============ union kernel: y = x@W (bf16 out)  ||  per-(bucket,chunk) counts ============
// Blocks [0, GEMM_BLOCKS): GEMM, 64 rows each (16 waves x 4 rows).
// Blocks [GEMM_BLOCKS, GEMM_BLOCKS+nblk): edge-count histogram + btot atomics.
__global__ __launch_bounds__(1024) void gemm_count(
    const float* __restrict__ x, const float* __restrict__ W,
    unsigned short* __restrict__ yh,
    const int* __restrict__ erow, unsigned short* __restrict__ cnts,
    int* __restrict__ btot, int n_edges, int nblk)
{
    __shared__ float4 Wl[64][16];
    __shared__ float  s[16][4][68];
    __shared__ int    cnt[NBUCK];

    const int t = threadIdx.x;
    if ((int)blockIdx.x < GEMM_BLOCKS) {
        // ---------- GEMM part ----------
        ((float4*)Wl)[t] = ((const float4*)W)[t];          // 1024 float4 = whole W

        const int wid  = t >> 6;
        const int lane = t & 63;
        const int sub  = lane >> 4;
        const int l    = lane & 15;
        const long base = (long)blockIdx.x * 64 + wid * 4; // 4 rows per wave
        const bool valid = (base + 3 < N_NODES);           // N_NODES % 4 == 0

        float4 sv = {0.f, 0.f, 0.f, 0.f};
        if (valid) sv = *reinterpret_cast<const float4*>(x + base * FDIM + lane * 4);
        *reinterpret_cast<float4*>(&s[wid][lane >> 4][(lane & 15) * 4]) = sv;
        __syncthreads();

        if (valid) {
            float4 acc = {0.f, 0.f, 0.f, 0.f};
            const float* srow = s[wid][sub];
            #pragma unroll
            for (int k = 0; k < FDIM; ++k) {
                const float a = srow[k];
                const float4 w = Wl[k][l];
                acc.x += a * w.x; acc.y += a * w.y; acc.z += a * w.z; acc.w += a * w.w;
            }
            ushort4 h;
            h.x = f2bf(acc.x); h.y = f2bf(acc.y); h.z = f2bf(acc.z); h.w = f2bf(acc.w);
            *reinterpret_cast<ushort4*>(yh + (size_t)(base + sub) * FDIM + l * 4) = h;
        }
    } else {
        // ---------- count part ----------
        const int blk = (int)blockIdx.x - GEMM_BLOCKS;
        for (int i = t; i < NBUCK; i += 1024) cnt[i] = 0;
        __syncthreads();
        const int beg = blk * EDGES_PER_BLK;
        const int end = min(beg + EDGES_PER_BLK, n_edges);
        for (int i = beg + t; i < end; i += 1024)
            atomicAdd(&cnt[erow[i] >> 6], 1);
        __syncthreads();
        for (int b = t; b < NBUCK; b += 1024) {
            const int c = cnt[b];
            cnts[b * nblk + blk] = (unsigned short)c;
            if (c) atomicAdd(&btot[b], c);
        }
    }
}

// ============ merged scans: per-bucket prefix (blocks 0..NBUCK-1) + btot scan (block NBUCK) ============
__global__ __launch_bounds__(256) void scan_bb(
    unsigned short* __restrict__ cnts, const int* __restrict__ btot,
    int* __restrict__ bbase, int n_edges, int nblk)
{
    __shared__ int ssum[256];
    const int b = blockIdx.x, t = threadIdx.x;

    if (b < NBUCK) {
        // within-bucket exclusive scan over nblk ushort counts
        const int c = (t < nblk) ? (int)cnts[b * nblk + t] : 0;
        ssum[t] = c;
        __syncthreads();
        for (int off = 1; off < 256; off <<= 1) {
            int v = (t >= off) ? ssum[t - off] : 0;
            __syncthreads();
            ssum[t] += v;
            __syncthreads();
        }
        if (t < nblk) cnts[b * nblk + t] = (unsigned short)(ssum[t] - c);
    } else {
        // exclusive scan of btot -> bbase (SCAN_C elems/thread)
        int v[SCAN_C];
        int s = 0;
        #pragma unroll
        for (int k = 0; k < SCAN_C; ++k) {
            const int idx = t * SCAN_C + k;
            v[k] = (idx < NBUCK) ? btot[idx] : 0;
            s += v[k];
        }
        ssum[t] = s;
        __syncthreads();
        for (int off = 1; off < 256; off <<= 1) {
            int vv = (t >= off) ? ssum[t - off] : 0;
            __syncthreads();
            ssum[t] += vv;
            __syncthreads();
        }
        int base = ssum[t] - s;                 // exclusive across threads
        #pragma unroll
        for (int k = 0; k < SCAN_C; ++k) {
            const int idx = t * SCAN_C + k;
            if (idx < NBUCK) bbase[idx] = base;
            base += v[k];
        }
        if (t == 0) bbase[NBUCK] = n_edges;     // sentinel
    }
}

// ============ bin via block-private segments (round-16 verified) ============
__global__ __launch_bounds__(1024) void bin_pass2(
    const int* __restrict__ erow, const int* __restrict__ ecol,
    const float* __restrict__ eval, const unsigned short* __restrict__ cnts,
    const int* __restrict__ bbase, int2* __restrict__ cvbin,
    int n_edges, int nblk)
{
    __shared__ int cur[NBUCK];
    const int blk = blockIdx.x, t = threadIdx.x;
    for (int b = t; b < NBUCK; b += 1024)
        cur[b] = bbase[b] + (int)cnts[b * nblk + blk];
    __syncthreads();
    const int beg = blk * EDGES_PER_BLK;
    const int end = min(beg + EDGES_PER_BLK, n_edges);
    for (int i = beg + t; i < end; i += 1024) {
        int r = erow[i];
        int b = r >> 6;
        int pos = atomicAdd(&cur[b], 1);            // LDS atomic
        cvbin[pos] = make_int2(ecol[i] | ((r & 63) << 20), __float_as_int(eval[i]));
    }
}

// ============ fused: LDS counting-sort + SpMM + bias + L2 norm (round-15/16 verified) ============
__global__ __launch_bounds__(256) void sort_spmm(
    const int* __restrict__ bbase, const int2* __restrict__ cvbin,
    const unsigned short* __restrict__ yh, const float* __restrict__ bias,
    float* __restrict__ out)
{
    __shared__ int2 se[BCAP];          // 12 KB sorted edges
    __shared__ int  hcnt[BROWS];
    __shared__ int  scn[BROWS];
    __shared__ int  rowbeg[BROWS];
    __shared__ int  cur[BROWS];

    const int b = blockIdx.x, t = threadIdx.x;
    const int beg = bbase[b];
    const int end = bbase[b + 1];
    const int n = end - beg;
    const bool fits = (n <= BCAP);     // >16 sigma margin; safety path below

    if (t < BROWS) hcnt[t] = 0;
    __syncthreads();

    if (fits) {
        for (int i = t; i < n; i += 256)
            atomicAdd(&hcnt[(cvbin[beg + i].x >> 20) & 63], 1);
        __syncthreads();
        if (t < BROWS) scn[t] = hcnt[t];
        __syncthreads();
        for (int off = 1; off < BROWS; off <<= 1) {
            int v = (t < BROWS && t >= off) ? scn[t - off] : 0;
            __syncthreads();
            if (t < BROWS) scn[t] += v;
            __syncthreads();
        }
        if (t < BROWS) { rowbeg[t] = scn[t] - hcnt[t]; cur[t] = scn[t] - hcnt[t]; }
        __syncthreads();
        for (int i = t; i < n; i += 256) {
            int2 e = cvbin[beg + i];                       // L2-hot re-read
            int pos = atomicAdd(&cur[(e.x >> 20) & 63], 1);
            se[pos] = e;
        }
        __syncthreads();
    }

    const int sg = t >> 4, l = t & 15;
    #pragma unroll
    for (int rr = 0; rr < 4; ++rr) {
        const int r = sg + 16 * rr;                        // coalesced out writes
        const int row = b * BROWS + r;
        float4 acc = {0.f, 0.f, 0.f, 0.f};

        if (fits) {
            const int rb = rowbeg[r];
            const int re = rb + hcnt[r];
            int it = rb;
            for (; it + 3 < re; it += 4) {
                const int2 ea = se[it];
                const int2 eb = se[it + 1];
                const int2 ec = se[it + 2];
                const int2 ed = se[it + 3];
                const ushort4 xa = *reinterpret_cast<const ushort4*>(yh + (size_t)(ea.x & 0xFFFFF) * FDIM + l * 4);
                const ushort4 xb = *reinterpret_cast<const ushort4*>(yh + (size_t)(eb.x & 0xFFFFF) * FDIM + l * 4);
                const ushort4 xc = *reinterpret_cast<const ushort4*>(yh + (size_t)(ec.x & 0xFFFFF) * FDIM + l * 4);
                const ushort4 xd = *reinterpret_cast<const ushort4*>(yh + (size_t)(ed.x & 0xFFFFF) * FDIM + l * 4);
                const float va = __int_as_float(ea.y);
                const float vb = __int_as_float(eb.y);
                const float vc = __int_as_float(ec.y);
                const float vd = __int_as_float(ed.y);
                acc.x += va * bf2f(xa.x); acc.y += va * bf2f(xa.y); acc.z += va * bf2f(xa.z); acc.w += va * bf2f(xa.w);
                acc.x += vb * bf2f(xb.x); acc.y += vb * bf2f(xb.y); acc.z += vb * bf2f(xb.z); acc.w += vb * bf2f(xb.w);
                acc.x += vc * bf2f(xc.x); acc.y += vc * bf2f(xc.y); acc.z += vc * bf2f(xc.z); acc.w += vc * bf2f(xc.w);
                acc.x += vd * bf2f(xd.x); acc.y += vd * bf2f(xd.y); acc.z += vd * bf2f(xd.z); acc.w += vd * bf2f(xd.w);
            }
            for (; it < re; ++it) {
                const int2 e = se[it];
                const float v = __int_as_float(e.y);
                const ushort4 xv = *reinterpret_cast<const ushort4*>(yh + (size_t)(e.x & 0xFFFFF) * FDIM + l * 4);
                acc.x += v * bf2f(xv.x); acc.y += v * bf2f(xv.y); acc.z += v * bf2f(xv.z); acc.w += v * bf2f(xv.w);
            }
        } else {
            // safety path (never taken for this input): filter full segment from global
            for (int i = beg; i < end; ++i) {
                const int2 e = cvbin[i];
                if (((e.x >> 20) & 63) == r) {
                    const float v = __int_as_float(e.y);
                    const ushort4 xv = *reinterpret_cast<const ushort4*>(yh + (size_t)(e.x & 0xFFFFF) * FDIM + l * 4);
                    acc.x += v * bf2f(xv.x); acc.y += v * bf2f(xv.y); acc.z += v * bf2f(xv.z); acc.w += v * bf2f(xv.w);
                }
            }
        }

        const float4 bv = *reinterpret_cast<const float4*>(bias + l * 4);
        acc.x += bv.x; acc.y += bv.y; acc.z += bv.z; acc.w += bv.w;

        float p = acc.x * acc.x + acc.y * acc.y + acc.z * acc.z + acc.w * acc.w;
        #pragma unroll
        for (int off = 1; off < 16; off <<= 1)
            p += __shfl_xor(p, off);
        const float inv = 1.0f / sqrtf(p);
        acc.x *= inv; acc.y *= inv; acc.z *= inv; acc.w *= inv;

        if (row < N_NODES)
            *reinterpret_cast<float4*>(out + (size_t)row * FDIM + l * 4) = acc;
    }
}

// ============ GEMM + bias + L2 normalize (fallback epilogue; verified) ============
__global__ __launch_bounds__(256) void gemm_norm(
    float* __restrict__ io, const float* __restrict__ W,
    const float* __restrict__ bias)
{
    __shared__ float4 Wl[64][16];
    __shared__ float4 bl[16];
    __shared__ float  s[4][4][68];

    const int t = threadIdx.x;
    for (int i = t; i < 64 * 16; i += 256)
        ((float4*)Wl)[i] = ((const float4*)W)[i];
    if (t < 16) bl[t] = ((const float4*)bias)[t];

    const int wid  = t >> 6;
    const int lane = t & 63;
    const int sub  = lane >> 4;
    const int l    = lane & 15;
    const long base = (long)blockIdx.x * 16 + wid * 4;

    float4 sv = *reinterpret_cast<const float4*>(io + base * FDIM + lane * 4);
    *reinterpret_cast<float4*>(&s[wid][lane >> 4][(lane & 15) * 4]) = sv;
    __syncthreads();

    float4 acc = {0.f, 0.f, 0.f, 0.f};
    const float* srow = s[wid][sub];
    #pragma unroll
    for (int k = 0; k < FDIM; ++k) {
        const float a = srow[k];
        const float4 w = Wl[k][l];
        acc.x += a * w.x; acc.y += a * w.y; acc.z += a * w.z; acc.w += a * w.w;
    }
    const float4 b = bl[l];
    acc.x += b.x; acc.y += b.y; acc.z += b.z; acc.w += b.w;

    float p = acc.x*acc.x + acc.y*acc.y + acc.z*acc.z + acc.w*acc.w;
    #pragma unroll
    for (int off = 1; off < 16; off <<= 1)
        p += __shfl_xor(p, off);
    const float inv = 1.0f / sqrtf(p);
    acc.x *= inv; acc.y *= inv; acc.z *= inv; acc.w *= inv;

    *reinterpret_cast<float4*>(io + (base + sub) * FDIM + l * 4) = acc;
}

extern "C" void kernel_launch(void* const* d_in, const int* in_sizes, int n_in,
                              void* d_out, int out_size, void* d_ws, size_t ws_size,
                              hipStream_t stream) {
    const float* x    = (const float*)d_in[0];
    const int*   erow = (const int*)d_in[1];
    const int*   ecol = (const int*)d_in[2];
    const float* eval = (const float*)d_in[3];
    const float* W    = (const float*)d_in[4];
    const float* bias = (const float*)d_in[5];
    float* out = (float*)d_out;
    const int n_edges = in_sizes[1];

    const int nblk = (n_edges + EDGES_PER_BLK - 1) / EDGES_PER_BLK;   // 196
    const size_t need_bf16 = (size_t)WS_XH_OFF + (size_t)N_NODES * FDIM * sizeof(short);
    const bool cnts_fit =
        (size_t)NBUCK * nblk * sizeof(unsigned short) <= WS_BBASE_OFF
        && nblk <= 256 && EDGES_PER_BLK <= 65535;

    if (ws_size >= need_bf16 && cnts_fit) {
        unsigned short* cnts = (unsigned short*)d_ws;
        int*  bbase  = (int*)((char*)d_ws + WS_BBASE_OFF);
        int*  btot   = (int*)((char*)d_ws + WS_BTOT_OFF);
        int2* cvbin  = (int2*)((char*)d_ws + WS_CV_OFF);
        unsigned short* yh = (unsigned short*)((char*)d_ws + WS_XH_OFF);

        hipMemsetAsync(btot, 0, NBUCK * sizeof(int), stream);
        gemm_count<<<GEMM_BLOCKS + nblk, 1024, 0, stream>>>(
            x, W, yh, erow, cnts, btot, n_edges, nblk);
        scan_bb<<<NBUCK + 1, 256, 0, stream>>>(cnts, btot, bbase, n_edges, nblk);
        bin_pass2<<<nblk, 1024, 0, stream>>>(erow, ecol, eval, cnts, bbase, cvbin,
                                             n_edges, nblk);
        sort_spmm<<<NBUCK, 256, 0, stream>>>(bbase, cvbin, yh, bias, out);
    } else {
        hipMemsetAsync(out, 0, (size_t)N_NODES * FDIM * sizeof(float), stream);
        long threads = (long)n_edges * 16;
        spmm_atomic<<<(int)((threads + 255) / 256), 256, 0, stream>>>(
            x, erow, ecol, eval, out, n_edges);
        gemm_norm<<<N_NODES / 16, 256, 0, stream>>>(out, W, bias);
    }
}

// Round 18
// 93.225 us; speedup vs baseline: 1.0271x; 1.0271x over previous
//
#include <hip/hip_runtime.h>

#define N_NODES 100000
#define FDIM 64
#define BROWS 64                                // rows per bucket
#define NBUCK ((N_NODES + BROWS - 1) / BROWS)   // 1563
#define EDGES_PER_BLK 6400
#define BCAP 1536                               // LDS sort capacity (mean 1024, sd 32)

// ---------------- ws layout ----------------
// cnts   : off 0       NBUCK*nblk ushort (781.5 KB; within-bucket exclusive prefixes)
// bbase  : off 800 KB  NBUCK+1 ints (bucket bases + sentinel)
// btot   : off 816 KB  NBUCK ints (bucket totals)
// cvbin  : off 1 MB    n_edges int2 {col | rowlo<<20, float_bits(val)}
// yh     : off 14 MB   N_NODES*FDIM bf16 of y = x@W
#define WS_BBASE_OFF (800u * 1024u)
#define WS_BTOT_OFF  (816u * 1024u)
#define WS_CV_OFF    (1024u * 1024u)
#define WS_XH_OFF    (14u * 1024u * 1024u)

__device__ __forceinline__ unsigned short f2bf(float f) {
    unsigned int u = __float_as_uint(f);
    return (unsigned short)((u + 0x7FFFu + ((u >> 16) & 1u)) >> 16);
}
__device__ __forceinline__ float bf2f(unsigned short h) {
    return __uint_as_float((unsigned int)h << 16);
}

// ============ fallback (round-4 verified): fp32 HW atomics ============
__global__ __launch_bounds__(256) void spmm_atomic(
    const float* __restrict__ x, const int* __restrict__ erow,
    const int* __restrict__ ecol, const float* __restrict__ eval,
    float* __restrict__ out, int n_edges)
{
    int tid = blockIdx.x * 256 + threadIdx.x;
    int e = tid >> 4, l = tid & 15;
    if (e >= n_edges) return;
    int row = erow[e], col = ecol[e];
    float v = eval[e];
    const float4 xv = *reinterpret_cast<const float4*>(x + (size_t)col * FDIM + l * 4);
    float* dst = out + (size_t)row * FDIM + l * 4;
    unsafeAtomicAdd(dst + 0, v * xv.x);
    unsafeAtomicAdd(dst + 1, v * xv.y);
    unsafeAtomicAdd(dst + 2, v * xv.z);
    unsafeAtomicAdd(dst + 3, v * xv.w);
}

// ============ y = x @ W, output bf16 (round-14 verified) ============
__global__ __launch_bounds__(256) void gemm_xw(
    const float* __restrict__ x, const float* __restrict__ W,
    unsigned short* __restrict__ yh)
{
    __shared__ float4 Wl[64][16];
    __shared__ float  s[4][4][68];

    const int t = threadIdx.x;
    for (int i = t; i < 64 * 16; i += 256)
        ((float4*)Wl)[i] = ((const float4*)W)[i];

    const int wid  = t >> 6;
    const int lane = t & 63;
    const int sub  = lane >> 4;
    const int l    = lane & 15;
    const long base = (long)blockIdx.x * 16 + wid * 4;

    float4 sv = *reinterpret_cast<const float4*>(x + base * FDIM + lane * 4);
    *reinterpret_cast<float4*>(&s[wid][lane >> 4][(lane & 15) * 4]) = sv;
    __syncthreads();

    float4 acc = {0.f, 0.f, 0.f, 0.f};
    const float* srow = s[wid][sub];
    #pragma unroll
    for (int k = 0; k < FDIM; ++k) {
        const float a = srow[k];
        const float4 w = Wl[k][l];
        acc.x += a * w.x; acc.y += a * w.y; acc.z += a * w.z; acc.w += a * w.w;
    }
    ushort4 h;
    h.x = f2bf(acc.x); h.y = f2bf(acc.y); h.z = f2bf(acc.z); h.w = f2bf(acc.w);
    *reinterpret_cast<ushort4*>(yh + (size_t)(base + sub) * FDIM + l * 4) = h;
}

// ============ per-(bucket,block) counts -> ushort (250-block grid) ============
__global__ __launch_bounds__(1024) void count_blocks(
    const int* __restrict__ erow, unsigned short* __restrict__ cnts,
    int n_edges, int nblk)
{
    __shared__ int cnt[NBUCK];
    const int blk = blockIdx.x, t = threadIdx.x;
    for (int i = t; i < NBUCK; i += 1024) cnt[i] = 0;
    __syncthreads();
    const int beg = blk * EDGES_PER_BLK;
    const int end = min(beg + EDGES_PER_BLK, n_edges);
    for (int i = beg + t; i < end; i += 1024)
        atomicAdd(&cnt[erow[i] >> 6], 1);
    __syncthreads();
    for (int b = t; b < NBUCK; b += 1024)
        cnts[b * nblk + blk] = (unsigned short)cnt[b];
}

// ============ within-bucket exclusive scan over ushort counts (round-16 verified) ============
__global__ __launch_bounds__(256) void scan_within_bucket(
    unsigned short* __restrict__ cnts, int* __restrict__ btot, int nblk)
{
    __shared__ int ssum[256];
    const int b = blockIdx.x, t = threadIdx.x;
    const int c = (t < nblk) ? (int)cnts[b * nblk + t] : 0;
    ssum[t] = c;
    __syncthreads();
    for (int off = 1; off < 256; off <<= 1) {
        int v = (t >= off) ? ssum[t - off] : 0;
        __syncthreads();
        ssum[t] += v;
        __syncthreads();
    }
    if (t < nblk) cnts[b * nblk + t] = (unsigned short)(ssum[t] - c);   // exclusive
    if (t == 255) btot[b] = ssum[255];
}

// ============ scan of bucket totals -> bbase (2 elems/thread; round-15 verified) ============
__global__ __launch_bounds__(1024) void scan_btot(
    const int* __restrict__ btot, int* __restrict__ bbase, int n_edges)
{
    __shared__ int ssum[1024];
    const int t = threadIdx.x;
    const int i0 = 2 * t, i1 = 2 * t + 1;
    const int v0 = (i0 < NBUCK) ? btot[i0] : 0;
    const int v1 = (i1 < NBUCK) ? btot[i1] : 0;
    const int s = v0 + v1;
    ssum[t] = s;
    __syncthreads();
    for (int off = 1; off < 1024; off <<= 1) {
        int v = (t >= off) ? ssum[t - off] : 0;
        __syncthreads();
        ssum[t] += v;
        __syncthreads();
    }
    int base = ssum[t] - s;                    // exclusive
    if (i0 < NBUCK) bbase[i0] = base;
    if (i1 < NBUCK) bbase[i1] = base + v0;
    if (t == 0) bbase[NBUCK] = n_edges;        // sentinel
}

// ============ bin via block-private segments (250-block grid) ============
__global__ __launch_bounds__(1024) void bin_pass2(
    const int* __restrict__ erow, const int* __restrict__ ecol,
    const float* __restrict__ eval, const unsigned short* __restrict__ cnts,
    const int* __restrict__ bbase, int2* __restrict__ cvbin,
    int n_edges, int nblk)
{
    __shared__ int cur[NBUCK];
    const int blk = blockIdx.x, t = threadIdx.x;
    for (int b = t; b < NBUCK; b += 1024)
        cur[b] = bbase[b] + (int)cnts[b * nblk + blk];
    __syncthreads();
    const int beg = blk * EDGES_PER_BLK;
    const int end = min(beg + EDGES_PER_BLK, n_edges);
    for (int i = beg + t; i < end; i += 1024) {
        int r = erow[i];
        int b = r >> 6;
        int pos = atomicAdd(&cur[b], 1);            // LDS atomic
        cvbin[pos] = make_int2(ecol[i] | ((r & 63) << 20), __float_as_int(eval[i]));
    }
}

// ============ fused: LDS counting-sort + SpMM + bias + L2 norm (round-15/16 verified) ============
__global__ __launch_bounds__(256) void sort_spmm(
    const int* __restrict__ bbase, const int2* __restrict__ cvbin,
    const unsigned short* __restrict__ yh, const float* __restrict__ bias,
    float* __restrict__ out)
{
    __shared__ int2 se[BCAP];          // 12 KB sorted edges
    __shared__ int  hcnt[BROWS];
    __shared__ int  scn[BROWS];
    __shared__ int  rowbeg[BROWS];
    __shared__ int  cur[BROWS];

    const int b = blockIdx.x, t = threadIdx.x;
    const int beg = bbase[b];
    const int end = bbase[b + 1];
    const int n = end - beg;
    const bool fits = (n <= BCAP);     // >16 sigma margin; safety path below

    if (t < BROWS) hcnt[t] = 0;
    __syncthreads();

    if (fits) {
        for (int i = t; i < n; i += 256)
            atomicAdd(&hcnt[(cvbin[beg + i].x >> 20) & 63], 1);
        __syncthreads();
        if (t < BROWS) scn[t] = hcnt[t];
        __syncthreads();
        for (int off = 1; off < BROWS; off <<= 1) {
            int v = (t < BROWS && t >= off) ? scn[t - off] : 0;
            __syncthreads();
            if (t < BROWS) scn[t] += v;
            __syncthreads();
        }
        if (t < BROWS) { rowbeg[t] = scn[t] - hcnt[t]; cur[t] = scn[t] - hcnt[t]; }
        __syncthreads();
        for (int i = t; i < n; i += 256) {
            int2 e = cvbin[beg + i];                       // L2-hot re-read
            int pos = atomicAdd(&cur[(e.x >> 20) & 63], 1);
            se[pos] = e;
        }
        __syncthreads();
    }

    const int sg = t >> 4, l = t & 15;
    #pragma unroll
    for (int rr = 0; rr < 4; ++rr) {
        const int r = sg + 16 * rr;                        // coalesced out writes
        const int row = b * BROWS + r;
        float4 acc = {0.f, 0.f, 0.f, 0.f};

        if (fits) {
            const int rb = rowbeg[r];
            const int re = rb + hcnt[r];
            int it = rb;
            for (; it + 3 < re; it += 4) {
                const int2 ea = se[it];
                const int2 eb = se[it + 1];
                const int2 ec = se[it + 2];
                const int2 ed = se[it + 3];
                const ushort4 xa = *reinterpret_cast<const ushort4*>(yh + (size_t)(ea.x & 0xFFFFF) * FDIM + l * 4);
                const ushort4 xb = *reinterpret_cast<const ushort4*>(yh + (size_t)(eb.x & 0xFFFFF) * FDIM + l * 4);
                const ushort4 xc = *reinterpret_cast<const ushort4*>(yh + (size_t)(ec.x & 0xFFFFF) * FDIM + l * 4);
                const ushort4 xd = *reinterpret_cast<const ushort4*>(yh + (size_t)(ed.x & 0xFFFFF) * FDIM + l * 4);
                const float va = __int_as_float(ea.y);
                const float vb = __int_as_float(eb.y);
                const float vc = __int_as_float(ec.y);
                const float vd = __int_as_float(ed.y);
                acc.x += va * bf2f(xa.x); acc.y += va * bf2f(xa.y); acc.z += va * bf2f(xa.z); acc.w += va * bf2f(xa.w);
                acc.x += vb * bf2f(xb.x); acc.y += vb * bf2f(xb.y); acc.z += vb * bf2f(xb.z); acc.w += vb * bf2f(xb.w);
                acc.x += vc * bf2f(xc.x); acc.y += vc * bf2f(xc.y); acc.z += vc * bf2f(xc.z); acc.w += vc * bf2f(xc.w);
                acc.x += vd * bf2f(xd.x); acc.y += vd * bf2f(xd.y); acc.z += vd * bf2f(xd.z); acc.w += vd * bf2f(xd.w);
            }
            for (; it < re; ++it) {
                const int2 e = se[it];
                const float v = __int_as_float(e.y);
                const ushort4 xv = *reinterpret_cast<const ushort4*>(yh + (size_t)(e.x & 0xFFFFF) * FDIM + l * 4);
                acc.x += v * bf2f(xv.x); acc.y += v * bf2f(xv.y); acc.z += v * bf2f(xv.z); acc.w += v * bf2f(xv.w);
            }
        } else {
            // safety path (never taken for this input): filter full segment from global
            for (int i = beg; i < end; ++i) {
                const int2 e = cvbin[i];
                if (((e.x >> 20) & 63) == r) {
                    const float v = __int_as_float(e.y);
                    const ushort4 xv = *reinterpret_cast<const ushort4*>(yh + (size_t)(e.x & 0xFFFFF) * FDIM + l * 4);
                    acc.x += v * bf2f(xv.x); acc.y += v * bf2f(xv.y); acc.z += v * bf2f(xv.z); acc.w += v * bf2f(xv.w);
                }
            }
        }

        const float4 bv = *reinterpret_cast<const float4*>(bias + l * 4);
        acc.x += bv.x; acc.y += bv.y; acc.z += bv.z; acc.w += bv.w;

        float p = acc.x * acc.x + acc.y * acc.y + acc.z * acc.z + acc.w * acc.w;
        #pragma unroll
        for (int off = 1; off < 16; off <<= 1)
            p += __shfl_xor(p, off);
        const float inv = 1.0f / sqrtf(p);
        acc.x *= inv; acc.y *= inv; acc.z *= inv; acc.w *= inv;

        if (row < N_NODES)
            *reinterpret_cast<float4*>(out + (size_t)row * FDIM + l * 4) = acc;
    }
}

// ============ GEMM + bias + L2 normalize (fallback epilogue; verified) ============
__global__ __launch_bounds__(256) void gemm_norm(
    float* __restrict__ io, const float* __restrict__ W,
    const float* __restrict__ bias)
{
    __shared__ float4 Wl[64][16];
    __shared__ float4 bl[16];
    __shared__ float  s[4][4][68];

    const int t = threadIdx.x;
    for (int i = t; i < 64 * 16; i += 256)
        ((float4*)Wl)[i] = ((const float4*)W)[i];
    if (t < 16) bl[t] = ((const float4*)bias)[t];

    const int wid  = t >> 6;
    const int lane = t & 63;
    const int sub  = lane >> 4;
    const int l    = lane & 15;
    const long base = (long)blockIdx.x * 16 + wid * 4;

    float4 sv = *reinterpret_cast<const float4*>(io + base * FDIM + lane * 4);
    *reinterpret_cast<float4*>(&s[wid][lane >> 4][(lane & 15) * 4]) = sv;
    __syncthreads();

    float4 acc = {0.f, 0.f, 0.f, 0.f};
    const float* srow = s[wid][sub];
    #pragma unroll
    for (int k = 0; k < FDIM; ++k) {
        const float a = srow[k];
        const float4 w = Wl[k][l];
        acc.x += a * w.x; acc.y += a * w.y; acc.z += a * w.z; acc.w += a * w.w;
    }
    const float4 b = bl[l];
    acc.x += b.x; acc.y += b.y; acc.z += b.z; acc.w += b.w;

    float p = acc.x*acc.x + acc.y*acc.y + acc.z*acc.z + acc.w*acc.w;
    #pragma unroll
    for (int off = 1; off < 16; off <<= 1)
        p += __shfl_xor(p, off);
    const float inv = 1.0f / sqrtf(p);
    acc.x *= inv; acc.y *= inv; acc.z *= inv; acc.w *= inv;

    *reinterpret_cast<float4*>(io + (base + sub) * FDIM + l * 4) = acc;
}

extern "C" void kernel_launch(void* const* d_in, const int* in_sizes, int n_in,
                              void* d_out, int out_size, void* d_ws, size_t ws_size,
                              hipStream_t stream) {
    const float* x    = (const float*)d_in[0];
    const int*   erow = (const int*)d_in[1];
    const int*   ecol = (const int*)d_in[2];
    const float* eval = (const float*)d_in[3];
    const float* W    = (const float*)d_in[4];
    const float* bias = (const float*)d_in[5];
    float* out = (float*)d_out;
    const int n_edges = in_sizes[1];

    const int nblk = (n_edges + EDGES_PER_BLK - 1) / EDGES_PER_BLK;   // 250
    const size_t need_bf16 = (size_t)WS_XH_OFF + (size_t)N_NODES * FDIM * sizeof(short);
    const bool cnts_fit =
        (size_t)NBUCK * nblk * sizeof(unsigned short) <= WS_BBASE_OFF
        && nblk <= 256 && EDGES_PER_BLK <= 65535;

    if (ws_size >= need_bf16 && cnts_fit) {
        unsigned short* cnts = (unsigned short*)d_ws;
        int*  bbase  = (int*)((char*)d_ws + WS_BBASE_OFF);
        int*  btot   = (int*)((char*)d_ws + WS_BTOT_OFF);
        int2* cvbin  = (int2*)((char*)d_ws + WS_CV_OFF);
        unsigned short* yh = (unsigned short*)((char*)d_ws + WS_XH_OFF);

        gemm_xw<<<N_NODES / 16, 256, 0, stream>>>(x, W, yh);
        count_blocks<<<nblk, 1024, 0, stream>>>(erow, cnts, n_edges, nblk);
        scan_within_bucket<<<NBUCK, 256, 0, stream>>>(cnts, btot, nblk);
        scan_btot<<<1, 1024, 0, stream>>>(btot, bbase, n_edges);
        bin_pass2<<<nblk, 1024, 0, stream>>>(erow, ecol, eval, cnts, bbase, cvbin,
                                             n_edges, nblk);
        sort_spmm<<<NBUCK, 256, 0, stream>>>(bbase, cvbin, yh, bias, out);
    } else {
        hipMemsetAsync(out, 0, (size_t)N_NODES * FDIM * sizeof(float), stream);
        long threads = (long)n_edges * 16;
        spmm_atomic<<<(int)((threads + 255) / 256), 256, 0, stream>>>(
            x, erow, ecol, eval, out, n_edges);
        gemm_norm<<<N_NODES / 16, 256, 0, stream>>>(out, W, bias);
    }
}